// Round 9
// baseline (155.236 us; speedup 1.0000x reference)
//
#include <hip/hip_runtime.h>

typedef unsigned short u16;
typedef unsigned char u8;
typedef unsigned int u32;
typedef __bf16 bf16x8 __attribute__((ext_vector_type(8)));
typedef float  f32x16 __attribute__((ext_vector_type(16)));
typedef int    i32x4  __attribute__((ext_vector_type(4)));
typedef int    i32x16 __attribute__((ext_vector_type(16)));

#define NB 4
#define NN 4096
#define ND 256

#define QPV (127.0f / 4.5f)        // pv quant scale
#define DPV (4.5f / 16129.0f)      // O dequant
#define QST (127.0f / 4.6f)        // state quant scale
#define DST (4.6f / 16129.0f)      // ds dequant
#define MAGIC 12582912.0f          // 1.5*2^23: fma(x,s,MAGIC) -> low byte = int8(x*s) rne

__device__ __forceinline__ u16 f2bf(float x) { return __builtin_bit_cast(u16, (__bf16)x); }
__device__ __forceinline__ u32 fbits(float x) { return __builtin_bit_cast(u32, x); }

__device__ __forceinline__ u32 packlow4(float a, float b, float c, float d) {
    u32 p = __builtin_amdgcn_perm(fbits(b), fbits(a), 0x00000400u);
    u32 q = __builtin_amdgcn_perm(fbits(d), fbits(c), 0x00000400u);
    return __builtin_amdgcn_perm(q, p, 0x05040100u);
}

// ws layout:
//  kq8 : [b*128+strip][s8][lane64][16B]    i8 val frags (A/B operand), 4 MB
//  vp8 : [b*128+strip][slot9][lane64][16B] i8 frags: slot0..7 = pv^T, slot8 = state bcast, 4.5 MB
//  wv  : [es8][s16][lane64][8]             bf16 Wv^T frags, 128 KB
//  srow: [b*4096+n] f32 = rowmax/127, 64 KB

// ---- misc: Wv^T bf16 frags (blocks 0..7) + state broadcast i8 frags (blocks 8..11) ----
__global__ __launch_bounds__(256) void k_misc(const float* __restrict__ Wv,
                                              const float* __restrict__ state,
                                              u16* __restrict__ wv, u8* __restrict__ vp8) {
    int tid = threadIdx.x;
    int bid = blockIdx.x;
    if (bid < 8) {
        __shared__ u16 t2[256 * 33];
        int es = bid, e0 = es * 32;
        #pragma unroll
        for (int k = 0; k < 8; k++) {
            int idx = tid + k * 256;
            int row = idx >> 3, c4 = idx & 7;
            float4 v = *(const float4*)(Wv + row * 256 + e0 + c4 * 4);
            u16* p = t2 + row * 33 + c4 * 4;
            p[0] = f2bf(v.x); p[1] = f2bf(v.y); p[2] = f2bf(v.z); p[3] = f2bf(v.w);
        }
        __syncthreads();
        u16* dst = wv + (size_t)es * 16 * 512;
        #pragma unroll
        for (int k = 0; k < 4; k++) {
            int flat = tid + k * 256;
            int s = flat >> 6, l = flat & 63;
            int l31 = l & 31, h = l >> 5;
            union { u16 o[8]; uint4 q; } u;
            #pragma unroll
            for (int j = 0; j < 8; j++) u.o[j] = t2[(s * 16 + h * 8 + j) * 33 + l31];
            *(uint4*)(dst + (size_t)flat * 8) = u.q;
        }
    } else {
        int b = bid - 8;
        __shared__ u8 qs[4096];
        #pragma unroll
        for (int k = 0; k < 16; k++) {
            int i = tid + k * 256;
            float x = fminf(fmaxf(state[b * 4096 + i] * QST, -127.0f), 127.0f);
            qs[i] = (u8)(fbits(x + MAGIC) & 255);
        }
        __syncthreads();
        #pragma unroll
        for (int k = 0; k < 32; k++) {
            int chunk = tid + k * 256;
            int strip = chunk >> 6, lane = chunk & 63, h = (lane >> 5) & 1;
            i32x4 v = *(const i32x4*)(qs + strip * 32 + h * 16);
            *(i32x4*)(vp8 + ((size_t)((b * 128 + strip) * 9 + 8)) * 1024 + (chunk & 63) * 16) = v;
        }
    }
}

// ---- pv2: fused val pack (rowmax + i8 frags + srow) AND pv GEMM -> i8 frags ----
// block = 64 val rows (2 strips), 256 thr = 4 waves; wave handles 2 e-strips.
#define TFS 260                                  // f32 LDS row stride (16B-aligned)
__global__ __launch_bounds__(256) void k_pv2(const float* __restrict__ val,
                                             const u16* __restrict__ wv,
                                             u8* __restrict__ kq8, u8* __restrict__ vp8,
                                             float* __restrict__ srow) {
    __shared__ float tf[64 * TFS];               // 65 KB f32 stage
    __shared__ float rmax[64];
    __shared__ u8 tp[4][32 * 48];                // per-wave transpose scratch

    int tid = threadIdx.x;
    int w = tid >> 6, lane = tid & 63;
    int l31 = lane & 31, h = lane >> 5;
    int bs = blockIdx.x;                         // [0,256): b*64 + loc; rows bs*64..+63

    // stage 64 rows of f32 val
    const float* src = val + (size_t)bs * 64 * 256;
    #pragma unroll
    for (int k = 0; k < 16; k++) {
        int idx = tid + k * 256;                 // 4096 float4
        int row = idx >> 6, c4 = idx & 63;
        float4 v = *(const float4*)(src + row * 256 + c4 * 4);
        *(float4*)(tf + row * TFS + c4 * 4) = v;
    }
    __syncthreads();

    // per-row max|.| (4 threads/row, float4 scans)
    {
        int row = tid >> 2, seg = tid & 3;
        float m = 0.0f;
        #pragma unroll
        for (int i = 0; i < 16; i++) {
            float4 v = *(const float4*)(tf + row * TFS + seg * 4 + i * 16);
            m = fmaxf(fmaxf(fabsf(v.x), fabsf(v.y)), fmaxf(fmaxf(fabsf(v.z), fabsf(v.w)), m));
        }
        m = fmaxf(m, __shfl_xor(m, 1));
        m = fmaxf(m, __shfl_xor(m, 2));
        if (seg == 0) {
            m = fmaxf(m, 1e-20f);
            rmax[row] = m;
            srow[bs * 64 + row] = m * (1.0f / 127.0f);
        }
    }
    __syncthreads();

    // i8 val frags (per-row scale), 1024 frag-lanes of 16B
    #pragma unroll
    for (int k = 0; k < 4; k++) {
        int flat = tid + k * 256;
        int strip = flat >> 9, rest = flat & 511;
        int s = rest >> 6, l = rest & 63;
        int fl31 = l & 31, fh = l >> 5;
        int row = strip * 32 + fl31;
        float r127 = 127.0f / rmax[row];
        const float* p = tf + row * TFS + s * 32 + fh * 16;
        u32 d[4];
        #pragma unroll
        for (int g = 0; g < 4; g++)
            d[g] = packlow4(fmaf(p[4 * g + 0], r127, MAGIC), fmaf(p[4 * g + 1], r127, MAGIC),
                            fmaf(p[4 * g + 2], r127, MAGIC), fmaf(p[4 * g + 3], r127, MAGIC));
        *(uint4*)(kq8 + ((size_t)(bs * 2 + strip)) * 8192 + (size_t)(s * 64 + l) * 16) =
            make_uint4(d[0], d[1], d[2], d[3]);
    }

    // pv GEMM: acc[es_i][qt] over K=256; B frags built from f32 LDS, A frags from global wv
    f32x16 acc[2][2] = {};
    for (int s = 0; s < 16; s++) {
        bf16x8 bq[2];
        #pragma unroll
        for (int qt = 0; qt < 2; qt++) {
            const float* p = tf + (qt * 32 + l31) * TFS + s * 16 + h * 8;
            union { __bf16 e[8]; bf16x8 v; } u;
            #pragma unroll
            for (int j = 0; j < 8; j++) u.e[j] = (__bf16)p[j];
            bq[qt] = u.v;
        }
        #pragma unroll
        for (int ei = 0; ei < 2; ei++) {
            int es = w * 2 + ei;
            bf16x8 af = *(const bf16x8*)(wv + (size_t)(es * 16 + s) * 512 + lane * 8);
            acc[ei][0] = __builtin_amdgcn_mfma_f32_32x32x16_bf16(af, bq[0], acc[ei][0], 0, 0, 0);
            acc[ei][1] = __builtin_amdgcn_mfma_f32_32x32x16_bf16(af, bq[1], acc[ei][1], 0, 0, 0);
        }
    }
    // quantize + transpose to B-operand frag order (within-wave LDS, no barriers)
    u8* myp = tp[w];
    #pragma unroll
    for (int ei = 0; ei < 2; ei++) {
        int es = w * 2 + ei;
        #pragma unroll
        for (int qt = 0; qt < 2; qt++) {
            #pragma unroll
            for (int r = 0; r < 16; r++) {
                int erow = (r & 3) + 8 * (r >> 2) + 4 * h;
                float x = fminf(fmaxf(acc[ei][qt][r] * QPV, -127.0f), 127.0f);
                myp[erow * 48 + l31] = (u8)(fbits(x + MAGIC) & 255);
            }
            i32x4 v = *(const i32x4*)(myp + l31 * 48 + h * 16);
            *(i32x4*)(vp8 + ((size_t)((bs * 2 + qt) * 9 + es)) * 1024 + lane * 16) = v;
        }
    }
}

// ---- main: pure-register loop, K/V/state direct from L2; 512 thr = 2 strips x 4 mq ----
__global__ __launch_bounds__(512, 2) void k_main(const u8* __restrict__ kq8,
                                                 const u8* __restrict__ vp8,
                                                 const float* __restrict__ srow,
                                                 float* __restrict__ ds_out,
                                                 float* __restrict__ dval_out) {
    __shared__ int red[2 * 8192];                // 64 KB epilogue scratch (per strip 32 KB)
    __shared__ int dsqi[2][4][32];

    int tid = threadIdx.x;
    int w = tid >> 6, lane = tid & 63;
    int l31 = lane & 31, h = lane >> 5;
    int strip = w & 1, mq = w >> 1;

    int id = blockIdx.x;                         // [0,256)
    int xcd = id & 7;
    int bb = xcd >> 1;
    int t6 = ((xcd & 1) << 5) | (id >> 3);       // [0,64)
    int q0 = t6 * 64;
    size_t bbase = (size_t)bb * 128;

    // resident Q frags for this strip
    i32x4 qf[8];
    {
        const u8* qsrc = kq8 + (bbase + t6 * 2 + strip) * 8192 + lane * 16;
        #pragma unroll
        for (int s = 0; s < 8; s++) qf[s] = *(const i32x4*)(qsrc + (size_t)s * 1024);
    }
    float srq = srow[bb * 4096 + q0 + strip * 32 + l31];

    i32x16 oacc[8] = {};
    i32x16 dsa = {};

    for (int mt = 0; mt < 32; mt++) {
        // K + V + state frags, straight from L2 (lane-linear 16B loads)
        const u8* kb = kq8 + (bbase + mt * 4 + mq) * 8192 + lane * 16;
        const u8* vbG = vp8 + (bbase + mt * 4 + mq) * 9216 + lane * 16;
        i32x4 kf[8];
        #pragma unroll
        for (int s = 0; s < 8; s++) kf[s] = *(const i32x4*)(kb + (size_t)s * 1024);
        const float* srm = srow + bb * 4096 + mt * 128 + mq * 32;
        float4 sg[4];
        #pragma unroll
        for (int g = 0; g < 4; g++) sg[g] = *(const float4*)(srm + g * 8 + h * 4);

        // S^T = K x Q^T
        i32x16 sacc = {};
        #pragma unroll
        for (int s = 0; s < 8; s++)
            sacc = __builtin_amdgcn_mfma_i32_32x32x32_i8(kf[s], qf[s], sacc, 0, 0, 0);

        // dequant -> softsign -> magic-round to i8 -> v_perm pack
        float cf[16];
        #pragma unroll
        for (int r = 0; r < 16; r++) {
            float sm = ((const float*)&sg[r >> 2])[r & 3] * srq;
            float xs = (float)sacc[r] * sm;
            float p = xs * __builtin_amdgcn_rcpf(1.0f + fabsf(xs));
            cf[r] = fmaf(p, 127.0f, MAGIC);
        }
        u32 w0 = packlow4(cf[0], cf[1], cf[2], cf[3]);
        u32 w1 = packlow4(cf[4], cf[5], cf[6], cf[7]);
        u32 w2 = packlow4(cf[8], cf[9], cf[10], cf[11]);
        u32 w3 = packlow4(cf[12], cf[13], cf[14], cf[15]);
        u32 x0 = (u32)__shfl_xor((int)w0, 32);
        u32 x1 = (u32)__shfl_xor((int)w1, 32);
        u32 x2 = (u32)__shfl_xor((int)w2, 32);
        u32 x3 = (u32)__shfl_xor((int)w3, 32);
        union { u32 wd[4]; i32x4 v; } pu;
        if (h == 0) { pu.wd[0] = w0; pu.wd[1] = x0; pu.wd[2] = w1; pu.wd[3] = x1; }
        else        { pu.wd[0] = x2; pu.wd[1] = w2; pu.wd[2] = x3; pu.wd[3] = w3; }
        i32x4 pf = pu.v;

        // O += P x Vt + ds (V/state direct from L2; strip-pair waves share the lines via L1)
        #pragma unroll
        for (int et = 0; et < 8; et++) {
            i32x4 vf = *(const i32x4*)(vbG + (size_t)et * 1024);
            oacc[et] = __builtin_amdgcn_mfma_i32_32x32x32_i8(pf, vf, oacc[et], 0, 0, 0);
        }
        {
            i32x4 sf = *(const i32x4*)(vbG + (size_t)8 * 1024);
            dsa = __builtin_amdgcn_mfma_i32_32x32x32_i8(pf, sf, dsa, 0, 0, 0);
        }
    }

    // ---- epilogue: per-strip 4-way mq reduction (i32 exact) ----
    __syncthreads();
    if (l31 == 0) {
        #pragma unroll
        for (int r = 0; r < 16; r++) dsqi[strip][mq][(r & 3) + 8 * (r >> 2) + 4 * h] = dsa[r];
    }
    int* rd = red + strip * 8192;
    if (mq == 3) {
        #pragma unroll
        for (int et = 0; et < 8; et++)
            #pragma unroll
            for (int r = 0; r < 16; r++) {
                int row = (r & 3) + 8 * (r >> 2) + 4 * h;
                rd[row * 256 + et * 32 + l31] = oacc[et][r];
            }
    }
    __syncthreads();
    if (mq == 2) {
        #pragma unroll
        for (int et = 0; et < 8; et++)
            #pragma unroll
            for (int r = 0; r < 16; r++) {
                int row = (r & 3) + 8 * (r >> 2) + 4 * h;
                rd[row * 256 + et * 32 + l31] += oacc[et][r];
            }
    }
    __syncthreads();
    if (mq == 1) {
        #pragma unroll
        for (int et = 0; et < 8; et++)
            #pragma unroll
            for (int r = 0; r < 16; r++) {
                int row = (r & 3) + 8 * (r >> 2) + 4 * h;
                rd[row * 256 + et * 32 + l31] += oacc[et][r];
            }
    }
    __syncthreads();
    if (mq == 0) {
        #pragma unroll
        for (int et = 0; et < 8; et++)
            #pragma unroll
            for (int r = 0; r < 16; r++) {
                int row = (r & 3) + 8 * (r >> 2) + 4 * h;
                int sum = oacc[et][r] + rd[row * 256 + et * 32 + l31];
                dval_out[((size_t)(bb * 4096 + q0 + strip * 32 + row)) * 256 + et * 32 + l31] =
                    (float)sum * DPV;
            }
        if (lane < 32) {
            int d = dsqi[strip][0][lane] + dsqi[strip][1][lane] +
                    dsqi[strip][2][lane] + dsqi[strip][3][lane];
            ds_out[bb * 4096 + q0 + strip * 32 + lane] = (float)d * DST;
        }
    }
}

extern "C" void kernel_launch(void* const* d_in, const int* in_sizes, int n_in,
                              void* d_out, int out_size, void* d_ws, size_t ws_size,
                              hipStream_t stream) {
    const float* val   = (const float*)d_in[0];
    const float* state = (const float*)d_in[1];
    const float* Wv    = (const float*)d_in[2];

    float* ds_out   = (float*)d_out;
    float* dval_out = ds_out + NB * NN;

    u8*  kq8 = (u8*)d_ws;                                      // 4 MB
    u8*  vp8 = kq8 + (size_t)NB * NN * ND;                     // 4.5 MB
    u16* wv  = (u16*)(vp8 + (size_t)NB * 128 * 9216);          // 128 KB
    float* srow = (float*)(wv + 8 * 16 * 512);                 // 64 KB

    k_misc<<<12, 256, 0, stream>>>(Wv, state, wv, vp8);
    k_pv2<<<256, 256, 0, stream>>>(val, wv, kq8, vp8, srow);
    k_main<<<256, 512, 0, stream>>>(kq8, vp8, srow, ds_out, dval_out);
}